// Round 4
// baseline (44.573 us; speedup 1.0000x reference)
//
#include <hip/hip_runtime.h>
#include <hip/hip_bf16.h>

// y = upsample_nearest_2x2x2(conv1x1(x,W,b)); conv on small grid via bf16 MFMA, replicate 8x.
// x: [2][320][16][32][32] f32, W: [160][320] f32, b: [160] f32 -> out: [2][160][32][64][64] f32
// Grid: 1024 blocks = 512 spatial tiles (NT=32) x 2 batches; full CO=160 per block.
// Each x element is fetched from HBM exactly once; W (205 KB) is L2-resident.

#define CI     320
#define CO     160
#define S_IN   16384      // 16*32*32
#define KC     64         // K chunk = 2 MFMA K-steps
#define NT     32         // spatial tile per block (1 w-row)
#define NCHUNK (CI / KC)  // 5
#define MT     5          // M-tiles per wave (80 o = half of CO)

typedef __attribute__((ext_vector_type(8))) short short8;
typedef __attribute__((ext_vector_type(4))) float f32x4;

static __device__ __forceinline__ unsigned short f2bf(float f) {
    __hip_bfloat16 h = __float2bfloat16(f);   // RNE
    unsigned short u;
    __builtin_memcpy(&u, &h, 2);
    return u;
}
static __device__ __forceinline__ unsigned int pack2(float lo, float hi) {
    return (unsigned int)f2bf(lo) | ((unsigned int)f2bf(hi) << 16);
}

__global__ __launch_bounds__(256, 4) void fused_upconv_mfma(
    const float* __restrict__ x,
    const float* __restrict__ Wm,
    const float* __restrict__ bias,
    float* __restrict__ out)
{
    // bf16 tiles as u32 k-pairs, rows padded 32 -> 36 u32 (144 B, 16B-aligned)
    __shared__ unsigned int XsU[NT][36];    // [s][k/2]   4.5 KB
    __shared__ unsigned int WsU[CO][36];    // [o][k/2]  22.5 KB

    const int t  = threadIdx.x;
    const int bx = blockIdx.x;              // 0..1023
    const int tile = bx >> 1;               // 0..511
    const int b    = bx & 1;

    const int s_base = tile * NT;
    const float* xb  = x + (size_t)b * CI * S_IN;

    // ---- staging maps ----
    // X: kp = t>>3 (32 k-pairs), s4 = (t&7)*4 : 2 float4 loads (k=2kp,2kp+1; 4 s each)
    const int kp = t >> 3;
    const int s4 = (t & 7) * 4;
    float4 xr0, xr1;
    // W: 10 iters, idx = t + it*256 : o = idx>>4 (0..159), kq = idx&15 : 1 float4 each
    float4 wr[10];

    // prefetch chunk 0
    {
        xr0 = *(const float4*)&xb[(size_t)(2 * kp)     * S_IN + s_base + s4];
        xr1 = *(const float4*)&xb[(size_t)(2 * kp + 1) * S_IN + s_base + s4];
        #pragma unroll
        for (int it = 0; it < 10; ++it) {
            const int idx = t + it * 256;
            wr[it] = *(const float4*)&Wm[(size_t)(idx >> 4) * CI + (idx & 15) * 4];
        }
    }

    // ---- fragment indices ----
    const int lane = t & 63;
    const int wid  = t >> 6;        // wave id 0..3
    const int sh   = wid & 1;       // s-half: 16-s subtile
    const int ohh  = wid >> 1;      // o-half: 80 o's
    const int frow = lane & 15;
    const int fk   = lane >> 4;
    const int o_base = ohh * 80;

    f32x4 acc[MT];
    #pragma unroll
    for (int mt = 0; mt < MT; ++mt) acc[mt] = (f32x4){0.f, 0.f, 0.f, 0.f};

    const char* xrow = (const char*)(&XsU[sh * 16 + frow][0]) + fk * 16;

    for (int c = 0; c < NCHUNK; ++c) {
        __syncthreads();   // previous chunk's fragment reads complete

        // regs -> LDS (f32->bf16 convert here)
        {
            const float a0[4] = {xr0.x, xr0.y, xr0.z, xr0.w};
            const float a1[4] = {xr1.x, xr1.y, xr1.z, xr1.w};
            #pragma unroll
            for (int j = 0; j < 4; ++j)
                XsU[s4 + j][kp] = pack2(a0[j], a1[j]);
            #pragma unroll
            for (int it = 0; it < 10; ++it) {
                const int idx = t + it * 256;
                uint2 p = make_uint2(pack2(wr[it].x, wr[it].y), pack2(wr[it].z, wr[it].w));
                *(uint2*)&WsU[idx >> 4][2 * (idx & 15)] = p;
            }
        }
        __syncthreads();

        // prefetch next chunk (overlaps MFMA below)
        if (c < NCHUNK - 1) {
            const int kc = (c + 1) * KC;
            xr0 = *(const float4*)&xb[(size_t)(kc + 2 * kp)     * S_IN + s_base + s4];
            xr1 = *(const float4*)&xb[(size_t)(kc + 2 * kp + 1) * S_IN + s_base + s4];
            #pragma unroll
            for (int it = 0; it < 10; ++it) {
                const int idx = t + it * 256;
                wr[it] = *(const float4*)&Wm[(size_t)(idx >> 4) * CI + kc + (idx & 15) * 4];
            }
        }

        // 2 K-steps x 5 M-tiles
        #pragma unroll
        for (int st = 0; st < 2; ++st) {
            const short8 bfrag = *(const short8*)(xrow + st * 64);
            #pragma unroll
            for (int mt = 0; mt < MT; ++mt) {
                const short8 afrag =
                    *(const short8*)((const char*)(&WsU[o_base + mt * 16 + frow][0]) + st * 64 + fk * 16);
                acc[mt] = __builtin_amdgcn_mfma_f32_16x16x32_bf16(afrag, bfrag, acc[mt], 0, 0, 0);
            }
        }
    }

    // ---- epilogue: bias + replicate 8x; shfl-pair -> full float4 nontemporal stores ----
    const int s   = s_base + sh * 16 + frow;    // D col = s
    const int dd  = s >> 10;
    const int hh  = (s >> 5) & 31;
    const int wc  = s & 31;
    const int odd = lane & 1;
    const int wc0 = wc & ~1;

    #pragma unroll
    for (int mt = 0; mt < MT; ++mt) {
        #pragma unroll
        for (int j = 0; j < 4; ++j) {
            const int o = o_base + mt * 16 + fk * 4 + j;   // D row = o
            float v  = acc[mt][j] + bias[o];
            float vp = __shfl_xor(v, 1);
            float lo = odd ? vp : v;
            float hi = odd ? v : vp;
            f32x4 q = {lo, lo, hi, hi};
            // even lane writes d-row 2dd, odd lane 2dd+1; each writes h-rows 2hh, 2hh+1
            const size_t base = (((size_t)(b * CO + o) * 32) + (size_t)(2 * dd + odd)) * 4096
                              + (size_t)(2 * hh) * 64 + (size_t)(2 * wc0);
            __builtin_nontemporal_store(q, (f32x4*)&out[base]);
            __builtin_nontemporal_store(q, (f32x4*)&out[base + 64]);
        }
    }
}

extern "C" void kernel_launch(void* const* d_in, const int* in_sizes, int n_in,
                              void* d_out, int out_size, void* d_ws, size_t ws_size,
                              hipStream_t stream) {
    const float* x    = (const float*)d_in[0];
    const float* Wm   = (const float*)d_in[1];
    const float* bias = (const float*)d_in[2];
    float* out        = (float*)d_out;

    dim3 grid(1024);
    dim3 block(256);
    fused_upconv_mfma<<<grid, block, 0, stream>>>(x, Wm, bias, out);
}